// Round 5
// baseline (1984.948 us; speedup 1.0000x reference)
//
#include <hip/hip_runtime.h>

// PromptPool: B=32768 rows, D=1024, P=20 prompts, K=5 rounds.
// Phase split:
//   pp_pre    - normalize keys, VK/VV cross-dot tables
//   pp_kdots  - 20 key dots per row (f64 chains), keys in 80 KiB LDS,
//               2 blocks/CU -> spill-free at VGPR<=128. Writes sbuf lanes 0..19.
//   pp_vdots  - 20 val dots + self dot (f32 chains), vals in 80 KiB LDS,
//               2 blocks/CU. Writes sbuf lanes 20..40.
//   pp_decide - one LANE per row: K=5 analytic softmax/argmax loop in registers
//   pp_wsum   - original per-wave f64 commitment-sum grouping (stride 2048)
//   pp_bcast  - pure broadcast: out_sel[row,t] = vals[idx[row,t]], wave per task
//   pp_loss   - final reduction
//
// R5 fix: one 160-KiB-LDS kernel always loses the allocator game (cap 128 ->
// spills ~40 regs; cap 64 -> spills ~77). Split keys/vals into two 80-KiB
// kernels: live sets ~110 / ~60 fit the 128 cap, 2 blocks/CU real occupancy.
// Input read twice (+134 MB HBM) buys removal of ~2 GB scratch traffic.

#define D  1024
#define PP 20
#define SBS 44                 // sbuf row stride in floats (41 used, 16B-aligned)
#define NBK 512                // blocks for dot kernels (2 per CU)
#define TBK 512                // threads per block = 8 waves
#define NWK (NBK * (TBK / 64)) // 4096 waves, 8 rows each
#define NWSUM 2048             // commitment-sum grouping (original kernel's order)

// ---------------- kernel 1: precompute norm_keys, VK, VV ----------------
__global__ __launch_bounds__(1024) void pp_pre(
    const float* __restrict__ keys,
    const float* __restrict__ vals,
    float* __restrict__ nk,     // ws: normalized keys f32 [PP*D]
    float* __restrict__ vkf,    // ws: VK = v_q . k_norm_p, f32 [PP*PP]
    float* __restrict__ vvf)    // ws: VV = v_q . v_p,      f32 [PP*PP]
{
    __shared__ float nk_s[PP * D];
    __shared__ float nrm_s[PP];
    const int tid = threadIdx.x;

    if (tid < PP) {
        const float* kp = keys + tid * D;
        double s0 = 0.0, s1 = 0.0;
        for (int d = 0; d < D; d += 2) {
            s0 += (double)kp[d]     * (double)kp[d];
            s1 += (double)kp[d + 1] * (double)kp[d + 1];
        }
        nrm_s[tid] = sqrtf((float)(s0 + s1));
    }
    __syncthreads();

    for (int i = tid; i < PP * D; i += blockDim.x) {
        float x = keys[i] / nrm_s[i >> 10];
        nk_s[i] = x;
        nk[i]   = x;
    }
    __syncthreads();

    if (tid < 2 * PP * PP) {
        const int which = tid & 1;              // 0 -> VK, 1 -> VV
        const int rem   = tid >> 1;             // q*PP + p
        const int q = rem / PP, p = rem % PP;
        const float* vq    = vals + q * D;
        const float* other = which ? (vals + p * D) : (nk_s + p * D);
        double s0 = 0.0, s1 = 0.0;
        for (int d = 0; d < D; d += 2) {
            s0 += (double)vq[d]     * (double)other[d];
            s1 += (double)vq[d + 1] * (double)other[d + 1];
        }
        float r = (float)(s0 + s1);
        if (which) vvf[rem] = r; else vkf[rem] = r;
    }
}

// ---------------- kernel 2a: key dots (f64 chains), 80 KiB LDS ----------------
__global__ __launch_bounds__(TBK) void pp_kdots(
    const float* __restrict__ input,
    const float* __restrict__ nk,
    float* __restrict__ sbuf,   // [B][SBS]: lanes 0..19 -> s
    int B)
{
    __shared__ float s_keys[PP * D];   // 80 KiB -> 2 blocks/CU
    const int tid = threadIdx.x;
    {
        const float4* a = (const float4*)nk;
        float4* sa = (float4*)s_keys;
        for (int i = tid; i < PP * D / 4; i += TBK) sa[i] = a[i];
    }
    __syncthreads();

    const int lane = tid & 63;
    const int gw   = blockIdx.x * (TBK / 64) + (tid >> 6);

    int row = gw;
    if (row >= B) return;

    const float4* ip0 = (const float4*)(input + (size_t)row * D);
    float4 r0 = ip0[lane], r1 = ip0[lane + 64], r2 = ip0[lane + 128], r3 = ip0[lane + 192];

    while (row < B) {
        const int nrow = row + NWK;
        float4 n0 = r0, n1 = r1, n2 = r2, n3 = r3;
        if (nrow < B) {   // prefetch next row
            const float4* np = (const float4*)(input + (size_t)nrow * D);
            n0 = np[lane]; n1 = np[lane + 64]; n2 = np[lane + 128]; n3 = np[lane + 192];
        }

        float rv[16] = { r0.x,r0.y,r0.z,r0.w, r1.x,r1.y,r1.z,r1.w,
                         r2.x,r2.y,r2.z,r2.w, r3.x,r3.y,r3.z,r3.w };
        double rd[16];
#pragma unroll
        for (int i = 0; i < 16; i++) rd[i] = (double)rv[i];   // exact cvt, once

        float o = 0.f;
#pragma unroll
        for (int p = 0; p < PP; p++) {
            const float4* kp = (const float4*)(s_keys + p * D);
            float4 k0 = kp[lane], k1 = kp[lane + 64], k2 = kp[lane + 128], k3 = kp[lane + 192];
            float kk[16] = { k0.x,k0.y,k0.z,k0.w, k1.x,k1.y,k1.z,k1.w,
                             k2.x,k2.y,k2.z,k2.w, k3.x,k3.y,k3.z,k3.w };
            double acc = 0.0;
#pragma unroll
            for (int i = 0; i < 16; i++)
                acc = fma(rd[i], (double)kk[i], acc);         // same chain order
            float sp = (float)acc;
#pragma unroll
            for (int m = 1; m < 64; m <<= 1) sp += __shfl_xor(sp, m, 64);
            o = (lane == p) ? sp : o;
        }

        if (lane < PP) sbuf[(size_t)row * SBS + lane] = o;

        r0 = n0; r1 = n1; r2 = n2; r3 = n3;
        row = nrow;
    }
}

// ---------------- kernel 2b: val dots + self dot (f32), 80 KiB LDS -----------
__global__ __launch_bounds__(TBK) void pp_vdots(
    const float* __restrict__ input,
    const float* __restrict__ vals,
    float* __restrict__ sbuf,   // [B][SBS]: lanes 20..39 -> rvp, 40 -> ||x||^2
    int B)
{
    __shared__ float s_vals[PP * D];   // 80 KiB -> 2 blocks/CU
    const int tid = threadIdx.x;
    {
        const float4* b = (const float4*)vals;
        float4* sb = (float4*)s_vals;
        for (int i = tid; i < PP * D / 4; i += TBK) sb[i] = b[i];
    }
    __syncthreads();

    const int lane = tid & 63;
    const int gw   = blockIdx.x * (TBK / 64) + (tid >> 6);

    int row = gw;
    if (row >= B) return;

    const float4* ip0 = (const float4*)(input + (size_t)row * D);
    float4 r0 = ip0[lane], r1 = ip0[lane + 64], r2 = ip0[lane + 128], r3 = ip0[lane + 192];

    while (row < B) {
        const int nrow = row + NWK;
        float4 n0 = r0, n1 = r1, n2 = r2, n3 = r3;
        if (nrow < B) {   // prefetch next row
            const float4* np = (const float4*)(input + (size_t)nrow * D);
            n0 = np[lane]; n1 = np[lane + 64]; n2 = np[lane + 128]; n3 = np[lane + 192];
        }

        float rv[16] = { r0.x,r0.y,r0.z,r0.w, r1.x,r1.y,r1.z,r1.w,
                         r2.x,r2.y,r2.z,r2.w, r3.x,r3.y,r3.z,r3.w };

        // self dot (||input||^2), f32 chain as original, reduce immediately
        float sq = 0.f;
#pragma unroll
        for (int i = 0; i < 16; i++) sq = fmaf(rv[i], rv[i], sq);
#pragma unroll
        for (int m = 1; m < 64; m <<= 1) sq += __shfl_xor(sq, m, 64);

        float o = sq;   // lane 40 keeps this; lanes 20..39 overwritten below

#pragma unroll
        for (int p = 0; p < PP; p++) {
            const float4* vp = (const float4*)(s_vals + p * D);
            float4 v0 = vp[lane], v1 = vp[lane + 64], v2 = vp[lane + 128], v3 = vp[lane + 192];
            float vl[16] = { v0.x,v0.y,v0.z,v0.w, v1.x,v1.y,v1.z,v1.w,
                             v2.x,v2.y,v2.z,v2.w, v3.x,v3.y,v3.z,v3.w };
            float ab = 0.f;
#pragma unroll
            for (int i = 0; i < 16; i++) ab = fmaf(rv[i], vl[i], ab);
#pragma unroll
            for (int m = 1; m < 64; m <<= 1) ab += __shfl_xor(ab, m, 64);
            o = (lane == PP + p) ? ab : o;
        }

        if (lane >= PP && lane < 2 * PP + 1) sbuf[(size_t)row * SBS + lane] = o;

        r0 = n0; r1 = n1; r2 = n2; r3 = n3;
        row = nrow;
    }
}

// ---------------- kernel 3: decide (1 LANE per row) ----------------
__global__ __launch_bounds__(256) void pp_decide(
    const float* __restrict__ sbuf,   // [B][SBS]
    const float* __restrict__ vkf,
    const float* __restrict__ vvf,
    float* __restrict__ out_idx,      // [B*K] as float
    float* __restrict__ cmrow,        // [B] per-row commitment (f32, exact values)
    int B, int K)
{
    __shared__ float vk_s[PP * PP];
    __shared__ float vv_s[PP * PP];
    for (int i = threadIdx.x; i < PP * PP; i += 256) { vk_s[i] = vkf[i]; vv_s[i] = vvf[i]; }
    __syncthreads();
    const int row = blockIdx.x * 256 + threadIdx.x;
    if (row >= B) return;

    const float4* rp = (const float4*)(sbuf + (size_t)row * SBS);
    float s[PP], rvp[PP];
    {
        float4 a0 = rp[0], a1 = rp[1], a2 = rp[2], a3 = rp[3], a4 = rp[4];
        float4 b0 = rp[5], b1 = rp[6], b2 = rp[7], b3 = rp[8], b4 = rp[9];
        s[0]=a0.x;  s[1]=a0.y;  s[2]=a0.z;  s[3]=a0.w;
        s[4]=a1.x;  s[5]=a1.y;  s[6]=a1.z;  s[7]=a1.w;
        s[8]=a2.x;  s[9]=a2.y;  s[10]=a2.z; s[11]=a2.w;
        s[12]=a3.x; s[13]=a3.y; s[14]=a3.z; s[15]=a3.w;
        s[16]=a4.x; s[17]=a4.y; s[18]=a4.z; s[19]=a4.w;
        rvp[0]=b0.x;  rvp[1]=b0.y;  rvp[2]=b0.z;  rvp[3]=b0.w;
        rvp[4]=b1.x;  rvp[5]=b1.y;  rvp[6]=b1.z;  rvp[7]=b1.w;
        rvp[8]=b2.x;  rvp[9]=b2.y;  rvp[10]=b2.z; rvp[11]=b2.w;
        rvp[12]=b3.x; rvp[13]=b3.y; rvp[14]=b3.z; rvp[15]=b3.w;
        rvp[16]=b4.x; rvp[17]=b4.y; rvp[18]=b4.z; rvp[19]=b4.w;
    }
    float rn2 = ((const float*)rp)[2 * PP];

    float cm = 0.f;
    for (int t = 0; t < K; t++) {
        float nrm = sqrtf(rn2);
        float sims[PP];
#pragma unroll
        for (int p = 0; p < PP; p++) sims[p] = s[p] / nrm;
        float mx = sims[0];
#pragma unroll
        for (int p = 1; p < PP; p++) mx = fmaxf(mx, sims[p]);
        float e[PP];
        float denom = 0.f;
#pragma unroll
        for (int p = 0; p < PP; p++) { e[p] = expf(sims[p] - mx); denom += e[p]; }
        float best = -1.f; int bi = 0;
#pragma unroll
        for (int p = 0; p < PP; p++) {
            float pr = e[p] / denom;
            if (pr > best) { best = pr; bi = p; }
        }
        cm += best;
        out_idx[(size_t)row * K + t] = (float)bi;

        if (t + 1 < K) {
            float rvbi = rvp[0];
#pragma unroll
            for (int p = 1; p < PP; p++) rvbi = (p == bi) ? rvp[p] : rvbi;
            rn2 = rn2 - 2.f * rvbi + vv_s[bi * PP + bi];
#pragma unroll
            for (int p = 0; p < PP; p++) { s[p] -= vk_s[bi * PP + p]; rvp[p] -= vv_s[bi * PP + p]; }
        }
    }
    cmrow[row] = cm;
}

// ---------------- kernel 4: wsum (reproduce old per-wave f64 sum order) ------
__global__ __launch_bounds__(256) void pp_wsum(
    const float* __restrict__ cmrow, double* __restrict__ wsum, int B)
{
    const int g = blockIdx.x * 256 + threadIdx.x;   // 0..NWSUM-1
    if (g >= NWSUM) return;
    double s = 0.0;
    for (int r = g; r < B; r += NWSUM) s += (double)cmrow[r];  // same order as old csum
    wsum[g] = s;
}

// ---------------- kernel 5: broadcast writer (wave per (row,t) task) ---------
__global__ __launch_bounds__(256) void pp_bcast(
    const float* __restrict__ vals,
    const float* __restrict__ out_idx,
    float* __restrict__ out_sel,
    int nTask)
{
    const int lane = threadIdx.x & 63;
    const int wid  = blockIdx.x * 4 + (threadIdx.x >> 6);
    const int nw   = gridDim.x * 4;

    int task = wid;
    int bi = (task < nTask) ? (int)out_idx[task] : 0;
    while (task < nTask) {
        const int ntask = task + nw;
        const int nbi = (ntask < nTask) ? (int)out_idx[ntask] : 0;  // prefetch idx

        const float4* pv = (const float4*)(vals + (size_t)bi * D);
        float4* ob = (float4*)(out_sel + (size_t)task * D);
        float4 a = pv[lane], b = pv[lane + 64], c = pv[lane + 128], d = pv[lane + 192];
        ob[lane]       = a;
        ob[lane + 64]  = b;
        ob[lane + 128] = c;
        ob[lane + 192] = d;

        task = ntask; bi = nbi;
    }
}

// ---------------- kernel 6: loss reduce ----------------
__global__ __launch_bounds__(256) void pp_loss(
    const double* __restrict__ wsum, float* __restrict__ out_loss, int B)
{
    __shared__ double sh[4];
    const int tid = threadIdx.x;
    double s = 0.0;
    for (int i = tid; i < NWSUM; i += 256) s += wsum[i];
#pragma unroll
    for (int m = 1; m < 64; m <<= 1) s += __shfl_xor(s, m, 64);
    if ((tid & 63) == 0) sh[tid >> 6] = s;
    __syncthreads();
    if (tid == 0) {
        double tot = sh[0] + sh[1] + sh[2] + sh[3];
        out_loss[0] = (float)(-(tot / (double)B));
    }
}

extern "C" void kernel_launch(void* const* d_in, const int* in_sizes, int n_in,
                              void* d_out, int out_size, void* d_ws, size_t ws_size,
                              hipStream_t stream) {
    const float* input = (const float*)d_in[0];
    const float* keys  = (const float*)d_in[1];
    const float* vals  = (const float*)d_in[2];

    const int B = in_sizes[0] / D;                       // 32768
    const int K = (out_size - 1) / (B * (D + 1));        // 5

    float* out_sel  = (float*)d_out;
    const size_t selN = (size_t)B * K * D;
    float* out_loss = out_sel + selN;
    float* out_idx  = out_sel + selN + 1;

    char*  ws    = (char*)d_ws;
    float* nk    = (float*)ws;                           // PP*D f32 = 81920 B
    float* vkf   = nk + PP * D;                          // 400 f32
    float* vvf   = vkf + PP * PP;                        // 400 f32
    double* wsum = (double*)(ws + ((PP * D + 2 * PP * PP) * 4)); // 8-aligned

    // Large scratch lives INSIDE out_sel (regenerated in full by pp_bcast later):
    //   sbuf = [B][SBS] f32 (5.8 MB), cmrow = [B] f32 (128 KB) — far below selN.
    float* sbuf  = out_sel;
    float* cmrow = out_sel + (size_t)B * SBS;

    const int nTask = B * K;

    pp_pre   <<<1, 1024, 0, stream>>>(keys, vals, nk, vkf, vvf);
    pp_kdots <<<NBK, TBK, 0, stream>>>(input, nk, sbuf, B);
    pp_vdots <<<NBK, TBK, 0, stream>>>(input, vals, sbuf, B);
    pp_decide<<<(B + 255) / 256, 256, 0, stream>>>(sbuf, vkf, vvf, out_idx, cmrow, B, K);
    pp_wsum  <<<(NWSUM + 255) / 256, 256, 0, stream>>>(cmrow, wsum, B);
    pp_bcast <<<2048, 256, 0, stream>>>(vals, out_idx, out_sel, nTask);
    pp_loss  <<<1, 256, 0, stream>>>(wsum, out_loss, B);
}

// Round 6
// 387.618 us; speedup vs baseline: 5.1209x; 5.1209x over previous
//
#include <hip/hip_runtime.h>

// PromptPool: B=32768 rows, D=1024, P=20 prompts, K=5 rounds.
// Phase split:
//   pp_pre    - normalize keys, VK/VV cross-dot tables
//   pp_kdots  - 20 key dots per row (f64 chains), keys in 80 KiB LDS.
//   pp_vdots  - 20 val dots + self dot (f32 chains), vals in 80 KiB LDS.
//   pp_decide - one LANE per row: K=5 analytic softmax/argmax loop in registers
//   pp_wsum   - original per-wave f64 commitment-sum grouping (stride 2048)
//   pp_bcast  - pure broadcast: out_sel[row,t] = vals[idx[row,t]], wave per task
//   pp_loss   - final reduction
//
// R6 fix: kdots still spilled (FETCH 1.93GB / WRITE 468MB) because the FULLY
// UNROLLED p-loop let the pre-RA scheduler hoist 20 iterations of ds_read
// destinations (~320 VGPRs in flight) -> RA spilled the long-lived f64 rd[16].
// `#pragma unroll 1` bounds the hoist window to one iteration (live ~70 regs,
// spill-free); 4 independent b128 reads/iter + 16 waves/CU hide DS latency.
// Per-value op chains unchanged -> bit-identical (absmax 0.0).

#define D  1024
#define PP 20
#define SBS 44                 // sbuf row stride in floats (41 used, 16B-aligned)
#define NBK 512                // blocks for dot kernels (2 per CU)
#define TBK 512                // threads per block = 8 waves
#define NWK (NBK * (TBK / 64)) // 4096 waves, 8 rows each
#define NWSUM 2048             // commitment-sum grouping (original kernel's order)

// ---------------- kernel 1: precompute norm_keys, VK, VV ----------------
__global__ __launch_bounds__(1024) void pp_pre(
    const float* __restrict__ keys,
    const float* __restrict__ vals,
    float* __restrict__ nk,     // ws: normalized keys f32 [PP*D]
    float* __restrict__ vkf,    // ws: VK = v_q . k_norm_p, f32 [PP*PP]
    float* __restrict__ vvf)    // ws: VV = v_q . v_p,      f32 [PP*PP]
{
    __shared__ float nk_s[PP * D];
    __shared__ float nrm_s[PP];
    const int tid = threadIdx.x;

    if (tid < PP) {
        const float* kp = keys + tid * D;
        double s0 = 0.0, s1 = 0.0;
        for (int d = 0; d < D; d += 2) {
            s0 += (double)kp[d]     * (double)kp[d];
            s1 += (double)kp[d + 1] * (double)kp[d + 1];
        }
        nrm_s[tid] = sqrtf((float)(s0 + s1));
    }
    __syncthreads();

    for (int i = tid; i < PP * D; i += blockDim.x) {
        float x = keys[i] / nrm_s[i >> 10];
        nk_s[i] = x;
        nk[i]   = x;
    }
    __syncthreads();

    if (tid < 2 * PP * PP) {
        const int which = tid & 1;              // 0 -> VK, 1 -> VV
        const int rem   = tid >> 1;             // q*PP + p
        const int q = rem / PP, p = rem % PP;
        const float* vq    = vals + q * D;
        const float* other = which ? (vals + p * D) : (nk_s + p * D);
        double s0 = 0.0, s1 = 0.0;
        for (int d = 0; d < D; d += 2) {
            s0 += (double)vq[d]     * (double)other[d];
            s1 += (double)vq[d + 1] * (double)other[d + 1];
        }
        float r = (float)(s0 + s1);
        if (which) vvf[rem] = r; else vkf[rem] = r;
    }
}

// ---------------- kernel 2a: key dots (f64 chains), 80 KiB LDS ----------------
__global__ __launch_bounds__(TBK) void pp_kdots(
    const float* __restrict__ input,
    const float* __restrict__ nk,
    float* __restrict__ sbuf,   // [B][SBS]: lanes 0..19 -> s
    int B)
{
    __shared__ float s_keys[PP * D];   // 80 KiB -> 2 blocks/CU
    const int tid = threadIdx.x;
    {
        const float4* a = (const float4*)nk;
        float4* sa = (float4*)s_keys;
        for (int i = tid; i < PP * D / 4; i += TBK) sa[i] = a[i];
    }
    __syncthreads();

    const int lane = tid & 63;
    const int gw   = blockIdx.x * (TBK / 64) + (tid >> 6);

    int row = gw;
    if (row >= B) return;

    const float4* ip0 = (const float4*)(input + (size_t)row * D);
    float4 r0 = ip0[lane], r1 = ip0[lane + 64], r2 = ip0[lane + 128], r3 = ip0[lane + 192];

    while (row < B) {
        const int nrow = row + NWK;
        float4 n0 = r0, n1 = r1, n2 = r2, n3 = r3;
        if (nrow < B) {   // prefetch next row
            const float4* np = (const float4*)(input + (size_t)nrow * D);
            n0 = np[lane]; n1 = np[lane + 64]; n2 = np[lane + 128]; n3 = np[lane + 192];
        }

        float rv[16] = { r0.x,r0.y,r0.z,r0.w, r1.x,r1.y,r1.z,r1.w,
                         r2.x,r2.y,r2.z,r2.w, r3.x,r3.y,r3.z,r3.w };
        double rd[16];
#pragma unroll
        for (int i = 0; i < 16; i++) rd[i] = (double)rv[i];   // exact cvt, once

        float o = 0.f;
#pragma unroll 1
        for (int p = 0; p < PP; p++) {     // NOT unrolled: bounds sched hoisting
            const float4* kp = (const float4*)(s_keys + p * D);
            float4 k0 = kp[lane], k1 = kp[lane + 64], k2 = kp[lane + 128], k3 = kp[lane + 192];
            float kk[16] = { k0.x,k0.y,k0.z,k0.w, k1.x,k1.y,k1.z,k1.w,
                             k2.x,k2.y,k2.z,k2.w, k3.x,k3.y,k3.z,k3.w };
            double acc = 0.0;
#pragma unroll
            for (int i = 0; i < 16; i++)
                acc = fma(rd[i], (double)kk[i], acc);         // same chain order
            float sp = (float)acc;
#pragma unroll
            for (int m = 1; m < 64; m <<= 1) sp += __shfl_xor(sp, m, 64);
            o = (lane == p) ? sp : o;
        }

        if (lane < PP) sbuf[(size_t)row * SBS + lane] = o;

        r0 = n0; r1 = n1; r2 = n2; r3 = n3;
        row = nrow;
    }
}

// ---------------- kernel 2b: val dots + self dot (f32), 80 KiB LDS -----------
__global__ __launch_bounds__(TBK) void pp_vdots(
    const float* __restrict__ input,
    const float* __restrict__ vals,
    float* __restrict__ sbuf,   // [B][SBS]: lanes 20..39 -> rvp, 40 -> ||x||^2
    int B)
{
    __shared__ float s_vals[PP * D];   // 80 KiB -> 2 blocks/CU
    const int tid = threadIdx.x;
    {
        const float4* b = (const float4*)vals;
        float4* sb = (float4*)s_vals;
        for (int i = tid; i < PP * D / 4; i += TBK) sb[i] = b[i];
    }
    __syncthreads();

    const int lane = tid & 63;
    const int gw   = blockIdx.x * (TBK / 64) + (tid >> 6);

    int row = gw;
    if (row >= B) return;

    const float4* ip0 = (const float4*)(input + (size_t)row * D);
    float4 r0 = ip0[lane], r1 = ip0[lane + 64], r2 = ip0[lane + 128], r3 = ip0[lane + 192];

    while (row < B) {
        const int nrow = row + NWK;
        float4 n0 = r0, n1 = r1, n2 = r2, n3 = r3;
        if (nrow < B) {   // prefetch next row
            const float4* np = (const float4*)(input + (size_t)nrow * D);
            n0 = np[lane]; n1 = np[lane + 64]; n2 = np[lane + 128]; n3 = np[lane + 192];
        }

        float rv[16] = { r0.x,r0.y,r0.z,r0.w, r1.x,r1.y,r1.z,r1.w,
                         r2.x,r2.y,r2.z,r2.w, r3.x,r3.y,r3.z,r3.w };

        // self dot (||input||^2), f32 chain as original, reduce immediately
        float sq = 0.f;
#pragma unroll
        for (int i = 0; i < 16; i++) sq = fmaf(rv[i], rv[i], sq);
#pragma unroll
        for (int m = 1; m < 64; m <<= 1) sq += __shfl_xor(sq, m, 64);

        float o = sq;   // lane 40 keeps this; lanes 20..39 overwritten below

#pragma unroll 1
        for (int p = 0; p < PP; p++) {     // NOT unrolled: bounds sched hoisting
            const float4* vp = (const float4*)(s_vals + p * D);
            float4 v0 = vp[lane], v1 = vp[lane + 64], v2 = vp[lane + 128], v3 = vp[lane + 192];
            float vl[16] = { v0.x,v0.y,v0.z,v0.w, v1.x,v1.y,v1.z,v1.w,
                             v2.x,v2.y,v2.z,v2.w, v3.x,v3.y,v3.z,v3.w };
            float ab = 0.f;
#pragma unroll
            for (int i = 0; i < 16; i++) ab = fmaf(rv[i], vl[i], ab);
#pragma unroll
            for (int m = 1; m < 64; m <<= 1) ab += __shfl_xor(ab, m, 64);
            o = (lane == PP + p) ? ab : o;
        }

        if (lane >= PP && lane < 2 * PP + 1) sbuf[(size_t)row * SBS + lane] = o;

        r0 = n0; r1 = n1; r2 = n2; r3 = n3;
        row = nrow;
    }
}

// ---------------- kernel 3: decide (1 LANE per row) ----------------
__global__ __launch_bounds__(256) void pp_decide(
    const float* __restrict__ sbuf,   // [B][SBS]
    const float* __restrict__ vkf,
    const float* __restrict__ vvf,
    float* __restrict__ out_idx,      // [B*K] as float
    float* __restrict__ cmrow,        // [B] per-row commitment (f32, exact values)
    int B, int K)
{
    __shared__ float vk_s[PP * PP];
    __shared__ float vv_s[PP * PP];
    for (int i = threadIdx.x; i < PP * PP; i += 256) { vk_s[i] = vkf[i]; vv_s[i] = vvf[i]; }
    __syncthreads();
    const int row = blockIdx.x * 256 + threadIdx.x;
    if (row >= B) return;

    const float4* rp = (const float4*)(sbuf + (size_t)row * SBS);
    float s[PP], rvp[PP];
    {
        float4 a0 = rp[0], a1 = rp[1], a2 = rp[2], a3 = rp[3], a4 = rp[4];
        float4 b0 = rp[5], b1 = rp[6], b2 = rp[7], b3 = rp[8], b4 = rp[9];
        s[0]=a0.x;  s[1]=a0.y;  s[2]=a0.z;  s[3]=a0.w;
        s[4]=a1.x;  s[5]=a1.y;  s[6]=a1.z;  s[7]=a1.w;
        s[8]=a2.x;  s[9]=a2.y;  s[10]=a2.z; s[11]=a2.w;
        s[12]=a3.x; s[13]=a3.y; s[14]=a3.z; s[15]=a3.w;
        s[16]=a4.x; s[17]=a4.y; s[18]=a4.z; s[19]=a4.w;
        rvp[0]=b0.x;  rvp[1]=b0.y;  rvp[2]=b0.z;  rvp[3]=b0.w;
        rvp[4]=b1.x;  rvp[5]=b1.y;  rvp[6]=b1.z;  rvp[7]=b1.w;
        rvp[8]=b2.x;  rvp[9]=b2.y;  rvp[10]=b2.z; rvp[11]=b2.w;
        rvp[12]=b3.x; rvp[13]=b3.y; rvp[14]=b3.z; rvp[15]=b3.w;
        rvp[16]=b4.x; rvp[17]=b4.y; rvp[18]=b4.z; rvp[19]=b4.w;
    }
    float rn2 = ((const float*)rp)[2 * PP];

    float cm = 0.f;
    for (int t = 0; t < K; t++) {
        float nrm = sqrtf(rn2);
        float sims[PP];
#pragma unroll
        for (int p = 0; p < PP; p++) sims[p] = s[p] / nrm;
        float mx = sims[0];
#pragma unroll
        for (int p = 1; p < PP; p++) mx = fmaxf(mx, sims[p]);
        float e[PP];
        float denom = 0.f;
#pragma unroll
        for (int p = 0; p < PP; p++) { e[p] = expf(sims[p] - mx); denom += e[p]; }
        float best = -1.f; int bi = 0;
#pragma unroll
        for (int p = 0; p < PP; p++) {
            float pr = e[p] / denom;
            if (pr > best) { best = pr; bi = p; }
        }
        cm += best;
        out_idx[(size_t)row * K + t] = (float)bi;

        if (t + 1 < K) {
            float rvbi = rvp[0];
#pragma unroll
            for (int p = 1; p < PP; p++) rvbi = (p == bi) ? rvp[p] : rvbi;
            rn2 = rn2 - 2.f * rvbi + vv_s[bi * PP + bi];
#pragma unroll
            for (int p = 0; p < PP; p++) { s[p] -= vk_s[bi * PP + p]; rvp[p] -= vv_s[bi * PP + p]; }
        }
    }
    cmrow[row] = cm;
}

// ---------------- kernel 4: wsum (reproduce old per-wave f64 sum order) ------
__global__ __launch_bounds__(256) void pp_wsum(
    const float* __restrict__ cmrow, double* __restrict__ wsum, int B)
{
    const int g = blockIdx.x * 256 + threadIdx.x;   // 0..NWSUM-1
    if (g >= NWSUM) return;
    double s = 0.0;
    for (int r = g; r < B; r += NWSUM) s += (double)cmrow[r];  // same order as old csum
    wsum[g] = s;
}

// ---------------- kernel 5: broadcast writer (wave per (row,t) task) ---------
__global__ __launch_bounds__(256) void pp_bcast(
    const float* __restrict__ vals,
    const float* __restrict__ out_idx,
    float* __restrict__ out_sel,
    int nTask)
{
    const int lane = threadIdx.x & 63;
    const int wid  = blockIdx.x * 4 + (threadIdx.x >> 6);
    const int nw   = gridDim.x * 4;

    int task = wid;
    int bi = (task < nTask) ? (int)out_idx[task] : 0;
    while (task < nTask) {
        const int ntask = task + nw;
        const int nbi = (ntask < nTask) ? (int)out_idx[ntask] : 0;  // prefetch idx

        const float4* pv = (const float4*)(vals + (size_t)bi * D);
        float4* ob = (float4*)(out_sel + (size_t)task * D);
        float4 a = pv[lane], b = pv[lane + 64], c = pv[lane + 128], d = pv[lane + 192];
        ob[lane]       = a;
        ob[lane + 64]  = b;
        ob[lane + 128] = c;
        ob[lane + 192] = d;

        task = ntask; bi = nbi;
    }
}

// ---------------- kernel 6: loss reduce ----------------
__global__ __launch_bounds__(256) void pp_loss(
    const double* __restrict__ wsum, float* __restrict__ out_loss, int B)
{
    __shared__ double sh[4];
    const int tid = threadIdx.x;
    double s = 0.0;
    for (int i = tid; i < NWSUM; i += 256) s += wsum[i];
#pragma unroll
    for (int m = 1; m < 64; m <<= 1) s += __shfl_xor(s, m, 64);
    if ((tid & 63) == 0) sh[tid >> 6] = s;
    __syncthreads();
    if (tid == 0) {
        double tot = sh[0] + sh[1] + sh[2] + sh[3];
        out_loss[0] = (float)(-(tot / (double)B));
    }
}

extern "C" void kernel_launch(void* const* d_in, const int* in_sizes, int n_in,
                              void* d_out, int out_size, void* d_ws, size_t ws_size,
                              hipStream_t stream) {
    const float* input = (const float*)d_in[0];
    const float* keys  = (const float*)d_in[1];
    const float* vals  = (const float*)d_in[2];

    const int B = in_sizes[0] / D;                       // 32768
    const int K = (out_size - 1) / (B * (D + 1));        // 5

    float* out_sel  = (float*)d_out;
    const size_t selN = (size_t)B * K * D;
    float* out_loss = out_sel + selN;
    float* out_idx  = out_sel + selN + 1;

    char*  ws    = (char*)d_ws;
    float* nk    = (float*)ws;                           // PP*D f32 = 81920 B
    float* vkf   = nk + PP * D;                          // 400 f32
    float* vvf   = vkf + PP * PP;                        // 400 f32
    double* wsum = (double*)(ws + ((PP * D + 2 * PP * PP) * 4)); // 8-aligned

    // Large scratch lives INSIDE out_sel (regenerated in full by pp_bcast later):
    //   sbuf = [B][SBS] f32 (5.8 MB), cmrow = [B] f32 (128 KB) — far below selN.
    float* sbuf  = out_sel;
    float* cmrow = out_sel + (size_t)B * SBS;

    const int nTask = B * K;

    pp_pre   <<<1, 1024, 0, stream>>>(keys, vals, nk, vkf, vvf);
    pp_kdots <<<NBK, TBK, 0, stream>>>(input, nk, sbuf, B);
    pp_vdots <<<NBK, TBK, 0, stream>>>(input, vals, sbuf, B);
    pp_decide<<<(B + 255) / 256, 256, 0, stream>>>(sbuf, vkf, vvf, out_idx, cmrow, B, K);
    pp_wsum  <<<(NWSUM + 255) / 256, 256, 0, stream>>>(cmrow, wsum, B);
    pp_bcast <<<2048, 256, 0, stream>>>(vals, out_idx, out_sel, nTask);
    pp_loss  <<<1, 256, 0, stream>>>(wsum, out_loss, B);
}

// Round 7
// 386.893 us; speedup vs baseline: 5.1305x; 1.0019x over previous
//
#include <hip/hip_runtime.h>

// PromptPool: B=32768 rows, D=1024, P=20 prompts, K=5 rounds.
// Phase split:
//   pp_pre    - normalize keys, VK/VV cross-dot tables
//   pp_dots   - per row: self dot + 20 key dots (f64 chains, keys in 80 KiB LDS)
//               + 20 val dots (f32 chains, vals streamed from L2). One input
//               pass. All loops `unroll 1` (R6 lesson: bounded sched window
//               -> no spills). Writes sbuf [B][44] row-major.
//   pp_decide - one LANE per row: K=5 analytic softmax/argmax loop in registers
//   pp_wsum   - original per-wave f64 commitment-sum grouping (stride 2048)
//   pp_bcast  - pure broadcast: out_sel[row,t] = vals[idx[row,t]], wave per task
//   pp_loss   - final reduction
//
// R7: fuse vdots into kdots. vals (80 KB) are L2-resident; reading them via
// global loads overlaps the val-dot serving with the key loop's f64 VALU and
// DS work inside one kernel, and removes a second full 134 MB input pass.

#define D  1024
#define PP 20
#define SBS 44                 // sbuf row stride in floats (41 used, 16B-aligned)
#define NBK 512                // blocks for dots kernel (2 per CU, 80 KiB LDS)
#define TBK 512                // threads per block = 8 waves
#define NWK (NBK * (TBK / 64)) // 4096 waves, 8 rows each
#define NWSUM 2048             // commitment-sum grouping (original kernel's order)

// ---------------- kernel 1: precompute norm_keys, VK, VV ----------------
__global__ __launch_bounds__(1024) void pp_pre(
    const float* __restrict__ keys,
    const float* __restrict__ vals,
    float* __restrict__ nk,     // ws: normalized keys f32 [PP*D]
    float* __restrict__ vkf,    // ws: VK = v_q . k_norm_p, f32 [PP*PP]
    float* __restrict__ vvf)    // ws: VV = v_q . v_p,      f32 [PP*PP]
{
    __shared__ float nk_s[PP * D];
    __shared__ float nrm_s[PP];
    const int tid = threadIdx.x;

    if (tid < PP) {
        const float* kp = keys + tid * D;
        double s0 = 0.0, s1 = 0.0;
        for (int d = 0; d < D; d += 2) {
            s0 += (double)kp[d]     * (double)kp[d];
            s1 += (double)kp[d + 1] * (double)kp[d + 1];
        }
        nrm_s[tid] = sqrtf((float)(s0 + s1));
    }
    __syncthreads();

    for (int i = tid; i < PP * D; i += blockDim.x) {
        float x = keys[i] / nrm_s[i >> 10];
        nk_s[i] = x;
        nk[i]   = x;
    }
    __syncthreads();

    if (tid < 2 * PP * PP) {
        const int which = tid & 1;              // 0 -> VK, 1 -> VV
        const int rem   = tid >> 1;             // q*PP + p
        const int q = rem / PP, p = rem % PP;
        const float* vq    = vals + q * D;
        const float* other = which ? (vals + p * D) : (nk_s + p * D);
        double s0 = 0.0, s1 = 0.0;
        for (int d = 0; d < D; d += 2) {
            s0 += (double)vq[d]     * (double)other[d];
            s1 += (double)vq[d + 1] * (double)other[d + 1];
        }
        float r = (float)(s0 + s1);
        if (which) vvf[rem] = r; else vkf[rem] = r;
    }
}

// ------- kernel 2: all 41 dots per row (keys via LDS, vals via L2) ----------
__global__ __launch_bounds__(TBK) void pp_dots(
    const float* __restrict__ input,
    const float* __restrict__ vals,
    const float* __restrict__ nk,
    float* __restrict__ sbuf,   // [B][SBS]: 0..19 -> s, 20..39 -> rvp, 40 -> ||x||^2
    int B)
{
    __shared__ float s_keys[PP * D];   // 80 KiB -> 2 blocks/CU
    const int tid = threadIdx.x;
    {
        const float4* a = (const float4*)nk;
        float4* sa = (float4*)s_keys;
        for (int i = tid; i < PP * D / 4; i += TBK) sa[i] = a[i];
    }
    __syncthreads();

    const int lane = tid & 63;
    const int gw   = blockIdx.x * (TBK / 64) + (tid >> 6);

    int row = gw;
    if (row >= B) return;

    const float4* ip0 = (const float4*)(input + (size_t)row * D);
    float4 r0 = ip0[lane], r1 = ip0[lane + 64], r2 = ip0[lane + 128], r3 = ip0[lane + 192];

    while (row < B) {
        const int nrow = row + NWK;
        float4 n0 = r0, n1 = r1, n2 = r2, n3 = r3;
        if (nrow < B) {   // prefetch next row
            const float4* np = (const float4*)(input + (size_t)nrow * D);
            n0 = np[lane]; n1 = np[lane + 64]; n2 = np[lane + 128]; n3 = np[lane + 192];
        }

        float rv[16] = { r0.x,r0.y,r0.z,r0.w, r1.x,r1.y,r1.z,r1.w,
                         r2.x,r2.y,r2.z,r2.w, r3.x,r3.y,r3.z,r3.w };
        double rd[16];
#pragma unroll
        for (int i = 0; i < 16; i++) rd[i] = (double)rv[i];   // exact cvt, once

        // self dot (||input||^2), f32 chain as original, reduce immediately
        float sq = 0.f;
#pragma unroll
        for (int i = 0; i < 16; i++) sq = fmaf(rv[i], rv[i], sq);
#pragma unroll
        for (int m = 1; m < 64; m <<= 1) sq += __shfl_xor(sq, m, 64);

        float o = sq;   // lane 40 keeps this; lanes 0..39 overwritten below

        // ---- key dots: f64 chains, keys from LDS (NOT unrolled: R6 lesson) --
#pragma unroll 1
        for (int p = 0; p < PP; p++) {
            const float4* kp = (const float4*)(s_keys + p * D);
            float4 k0 = kp[lane], k1 = kp[lane + 64], k2 = kp[lane + 128], k3 = kp[lane + 192];
            float kk[16] = { k0.x,k0.y,k0.z,k0.w, k1.x,k1.y,k1.z,k1.w,
                             k2.x,k2.y,k2.z,k2.w, k3.x,k3.y,k3.z,k3.w };
            double acc = 0.0;
#pragma unroll
            for (int i = 0; i < 16; i++)
                acc = fma(rd[i], (double)kk[i], acc);         // same chain order
            float sp = (float)acc;
#pragma unroll
            for (int m = 1; m < 64; m <<= 1) sp += __shfl_xor(sp, m, 64);
            o = (lane == p) ? sp : o;
        }

        // ---- val dots: f32 chains, vals from L2 (80 KB resident) ----
#pragma unroll 1
        for (int p = 0; p < PP; p++) {
            const float4* vp = (const float4*)(vals + (size_t)p * D);
            float4 v0 = vp[lane], v1 = vp[lane + 64], v2 = vp[lane + 128], v3 = vp[lane + 192];
            float vl[16] = { v0.x,v0.y,v0.z,v0.w, v1.x,v1.y,v1.z,v1.w,
                             v2.x,v2.y,v2.z,v2.w, v3.x,v3.y,v3.z,v3.w };
            float ab = 0.f;
#pragma unroll
            for (int i = 0; i < 16; i++) ab = fmaf(rv[i], vl[i], ab);
#pragma unroll
            for (int m = 1; m < 64; m <<= 1) ab += __shfl_xor(ab, m, 64);
            o = (lane == PP + p) ? ab : o;
        }

        if (lane < 2 * PP + 1) sbuf[(size_t)row * SBS + lane] = o;  // 164B/row

        r0 = n0; r1 = n1; r2 = n2; r3 = n3;
        row = nrow;
    }
}

// ---------------- kernel 3: decide (1 LANE per row) ----------------
__global__ __launch_bounds__(256) void pp_decide(
    const float* __restrict__ sbuf,   // [B][SBS]
    const float* __restrict__ vkf,
    const float* __restrict__ vvf,
    float* __restrict__ out_idx,      // [B*K] as float
    float* __restrict__ cmrow,        // [B] per-row commitment (f32, exact values)
    int B, int K)
{
    __shared__ float vk_s[PP * PP];
    __shared__ float vv_s[PP * PP];
    for (int i = threadIdx.x; i < PP * PP; i += 256) { vk_s[i] = vkf[i]; vv_s[i] = vvf[i]; }
    __syncthreads();
    const int row = blockIdx.x * 256 + threadIdx.x;
    if (row >= B) return;

    const float4* rp = (const float4*)(sbuf + (size_t)row * SBS);
    float s[PP], rvp[PP];
    {
        float4 a0 = rp[0], a1 = rp[1], a2 = rp[2], a3 = rp[3], a4 = rp[4];
        float4 b0 = rp[5], b1 = rp[6], b2 = rp[7], b3 = rp[8], b4 = rp[9];
        s[0]=a0.x;  s[1]=a0.y;  s[2]=a0.z;  s[3]=a0.w;
        s[4]=a1.x;  s[5]=a1.y;  s[6]=a1.z;  s[7]=a1.w;
        s[8]=a2.x;  s[9]=a2.y;  s[10]=a2.z; s[11]=a2.w;
        s[12]=a3.x; s[13]=a3.y; s[14]=a3.z; s[15]=a3.w;
        s[16]=a4.x; s[17]=a4.y; s[18]=a4.z; s[19]=a4.w;
        rvp[0]=b0.x;  rvp[1]=b0.y;  rvp[2]=b0.z;  rvp[3]=b0.w;
        rvp[4]=b1.x;  rvp[5]=b1.y;  rvp[6]=b1.z;  rvp[7]=b1.w;
        rvp[8]=b2.x;  rvp[9]=b2.y;  rvp[10]=b2.z; rvp[11]=b2.w;
        rvp[12]=b3.x; rvp[13]=b3.y; rvp[14]=b3.z; rvp[15]=b3.w;
        rvp[16]=b4.x; rvp[17]=b4.y; rvp[18]=b4.z; rvp[19]=b4.w;
    }
    float rn2 = ((const float*)rp)[2 * PP];

    float cm = 0.f;
    for (int t = 0; t < K; t++) {
        float nrm = sqrtf(rn2);
        float sims[PP];
#pragma unroll
        for (int p = 0; p < PP; p++) sims[p] = s[p] / nrm;
        float mx = sims[0];
#pragma unroll
        for (int p = 1; p < PP; p++) mx = fmaxf(mx, sims[p]);
        float e[PP];
        float denom = 0.f;
#pragma unroll
        for (int p = 0; p < PP; p++) { e[p] = expf(sims[p] - mx); denom += e[p]; }
        float best = -1.f; int bi = 0;
#pragma unroll
        for (int p = 0; p < PP; p++) {
            float pr = e[p] / denom;
            if (pr > best) { best = pr; bi = p; }
        }
        cm += best;
        out_idx[(size_t)row * K + t] = (float)bi;

        if (t + 1 < K) {
            float rvbi = rvp[0];
#pragma unroll
            for (int p = 1; p < PP; p++) rvbi = (p == bi) ? rvp[p] : rvbi;
            rn2 = rn2 - 2.f * rvbi + vv_s[bi * PP + bi];
#pragma unroll
            for (int p = 0; p < PP; p++) { s[p] -= vk_s[bi * PP + p]; rvp[p] -= vv_s[bi * PP + p]; }
        }
    }
    cmrow[row] = cm;
}

// ---------------- kernel 4: wsum (reproduce old per-wave f64 sum order) ------
__global__ __launch_bounds__(256) void pp_wsum(
    const float* __restrict__ cmrow, double* __restrict__ wsum, int B)
{
    const int g = blockIdx.x * 256 + threadIdx.x;   // 0..NWSUM-1
    if (g >= NWSUM) return;
    double s = 0.0;
    for (int r = g; r < B; r += NWSUM) s += (double)cmrow[r];  // same order as old csum
    wsum[g] = s;
}

// ---------------- kernel 5: broadcast writer (wave per (row,t) task) ---------
__global__ __launch_bounds__(256) void pp_bcast(
    const float* __restrict__ vals,
    const float* __restrict__ out_idx,
    float* __restrict__ out_sel,
    int nTask)
{
    const int lane = threadIdx.x & 63;
    const int wid  = blockIdx.x * 4 + (threadIdx.x >> 6);
    const int nw   = gridDim.x * 4;

    int task = wid;
    int bi = (task < nTask) ? (int)out_idx[task] : 0;
    while (task < nTask) {
        const int ntask = task + nw;
        const int nbi = (ntask < nTask) ? (int)out_idx[ntask] : 0;  // prefetch idx

        const float4* pv = (const float4*)(vals + (size_t)bi * D);
        float4* ob = (float4*)(out_sel + (size_t)task * D);
        float4 a = pv[lane], b = pv[lane + 64], c = pv[lane + 128], d = pv[lane + 192];
        ob[lane]       = a;
        ob[lane + 64]  = b;
        ob[lane + 128] = c;
        ob[lane + 192] = d;

        task = ntask; bi = nbi;
    }
}

// ---------------- kernel 6: loss reduce ----------------
__global__ __launch_bounds__(256) void pp_loss(
    const double* __restrict__ wsum, float* __restrict__ out_loss, int B)
{
    __shared__ double sh[4];
    const int tid = threadIdx.x;
    double s = 0.0;
    for (int i = tid; i < NWSUM; i += 256) s += wsum[i];
#pragma unroll
    for (int m = 1; m < 64; m <<= 1) s += __shfl_xor(s, m, 64);
    if ((tid & 63) == 0) sh[tid >> 6] = s;
    __syncthreads();
    if (tid == 0) {
        double tot = sh[0] + sh[1] + sh[2] + sh[3];
        out_loss[0] = (float)(-(tot / (double)B));
    }
}

extern "C" void kernel_launch(void* const* d_in, const int* in_sizes, int n_in,
                              void* d_out, int out_size, void* d_ws, size_t ws_size,
                              hipStream_t stream) {
    const float* input = (const float*)d_in[0];
    const float* keys  = (const float*)d_in[1];
    const float* vals  = (const float*)d_in[2];

    const int B = in_sizes[0] / D;                       // 32768
    const int K = (out_size - 1) / (B * (D + 1));        // 5

    float* out_sel  = (float*)d_out;
    const size_t selN = (size_t)B * K * D;
    float* out_loss = out_sel + selN;
    float* out_idx  = out_sel + selN + 1;

    char*  ws    = (char*)d_ws;
    float* nk    = (float*)ws;                           // PP*D f32 = 81920 B
    float* vkf   = nk + PP * D;                          // 400 f32
    float* vvf   = vkf + PP * PP;                        // 400 f32
    double* wsum = (double*)(ws + ((PP * D + 2 * PP * PP) * 4)); // 8-aligned

    // Large scratch lives INSIDE out_sel (regenerated in full by pp_bcast later):
    //   sbuf = [B][SBS] f32 (5.8 MB), cmrow = [B] f32 (128 KB) — far below selN.
    float* sbuf  = out_sel;
    float* cmrow = out_sel + (size_t)B * SBS;

    const int nTask = B * K;

    pp_pre   <<<1, 1024, 0, stream>>>(keys, vals, nk, vkf, vvf);
    pp_dots  <<<NBK, TBK, 0, stream>>>(input, vals, nk, sbuf, B);
    pp_decide<<<(B + 255) / 256, 256, 0, stream>>>(sbuf, vkf, vvf, out_idx, cmrow, B, K);
    pp_wsum  <<<(NWSUM + 255) / 256, 256, 0, stream>>>(cmrow, wsum, B);
    pp_bcast <<<2048, 256, 0, stream>>>(vals, out_idx, out_sel, nTask);
    pp_loss  <<<1, 256, 0, stream>>>(wsum, out_loss, B);
}